// Round 10
// baseline (1053.218 us; speedup 1.0000x reference)
//
#include <hip/hip_runtime.h>
#include <hip/hip_fp16.h>
#include <math.h>

#define DD 128
#define SCAN_BLOCKS 256
#define SMAX_CAP 128

typedef _Float16 f16x8 __attribute__((ext_vector_type(8)));
typedef float f32x4 __attribute__((ext_vector_type(4)));

__device__ inline float wave_sum(float v){
#pragma unroll
  for (int m = 32; m >= 1; m >>= 1) v += __shfl_xor(v, m, 64);
  return v;
}
__device__ inline int wave_sum_i(int v){
#pragma unroll
  for (int m = 32; m >= 1; m >>= 1) v += __shfl_xor(v, m, 64);
  return v;
}

// ---- setup kernels -------------------------------------------------------

__global__ void k_edge_offsets(const int* __restrict__ edges, int nnz, int E,
                               int* __restrict__ eo){
  int e = blockIdx.x * blockDim.x + threadIdx.x;
  if (e > E) return;
  int lo = 0, hi = nnz;
  while (lo < hi){ int mid = (lo + hi) >> 1; if (edges[mid] < e) lo = mid + 1; else hi = mid; }
  eo[e] = lo;
}

__global__ void k_hist(const int* __restrict__ nodes, int nnz, int* __restrict__ dV){
  int k = blockIdx.x * blockDim.x + threadIdx.x;
  if (k < nnz) atomicAdd(&dV[nodes[k]], 1);
}

__global__ __launch_bounds__(256) void k_scan_partial(const int* __restrict__ dV, int N,
                                                      int* __restrict__ part){
  int b = blockIdx.x, t = threadIdx.x;
  int chunk = (N + SCAN_BLOCKS - 1) / SCAN_BLOCKS;
  int s0 = b * chunk, s1 = min(s0 + chunk, N);
  int sum = 0;
  for (int n = s0 + t; n < s1; n += 256) sum += dV[n];
  sum = wave_sum_i(sum);
  __shared__ int wred[4];
  int lane = t & 63, wid = t >> 6;
  if (lane == 0) wred[wid] = sum;
  __syncthreads();
  if (t == 0) part[b] = wred[0] + wred[1] + wred[2] + wred[3];
}

__global__ __launch_bounds__(SCAN_BLOCKS) void k_scan_blocksums(int* __restrict__ part){
  __shared__ int sh[SCAN_BLOCKS];
  int t = threadIdx.x;
  int v = part[t];
  sh[t] = v; __syncthreads();
  for (int off = 1; off < SCAN_BLOCKS; off <<= 1){
    int add = (t >= off) ? sh[t - off] : 0;
    __syncthreads();
    sh[t] += add;
    __syncthreads();
  }
  part[t] = sh[t] - v;
}

__global__ __launch_bounds__(256) void k_scan_apply(const int* __restrict__ dV, int N, int nnz,
    const int* __restrict__ partScan, int* __restrict__ no, int* __restrict__ nfill,
    float* __restrict__ degV){
  int b = blockIdx.x, t = threadIdx.x;
  int chunk = (N + SCAN_BLOCKS - 1) / SCAN_BLOCKS;
  int s0 = b * chunk, s1 = min(s0 + chunk, N);
  int lane = t & 63, wid = t >> 6;
  __shared__ int wtot[4];
  __shared__ int s_run;
  if (t == 0) s_run = partScan[b];
  __syncthreads();
  for (int base = s0; base < s1; base += 256){
    int n = base + t;
    int d = (n < s1) ? dV[n] : 0;
    int v = d;
#pragma unroll
    for (int off = 1; off < 64; off <<= 1){
      int o = __shfl_up(v, off, 64);
      if (lane >= off) v += o;
    }
    if (lane == 63) wtot[wid] = v;
    __syncthreads();
    int run0 = s_run;
    int woff = 0;
    for (int w = 0; w < wid; w++) woff += wtot[w];
    if (n < s1){
      int excl = run0 + woff + v - d;
      no[n] = excl; nfill[n] = excl;
      degV[n] = d > 0 ? 1.0f / sqrtf((float)d) : 1.0f;
    }
    int btot = wtot[0] + wtot[1] + wtot[2] + wtot[3];
    __syncthreads();
    if (t == 0) s_run = run0 + btot;
    __syncthreads();
  }
  if (b == 0 && t == 0) no[N] = nnz;
}

// merged perm+pack: scatter CSR payload directly
__global__ void k_permpack(const int* __restrict__ nodes, const int* __restrict__ edges,
                           const float* __restrict__ dist, const float* __restrict__ deg,
                           int nnz, int* __restrict__ nfill, float2* __restrict__ pack){
  int k = blockIdx.x * blockDim.x + threadIdx.x;
  if (k < nnz){
    int pos = atomicAdd(&nfill[nodes[k]], 1);
    pack[pos] = make_float2(__int_as_float(edges[k]), dist[k] + 64.f * deg[k]);
  }
}

__global__ void k_edge_deg(const int* __restrict__ nodes, const int* __restrict__ eo, int E,
                           const int* __restrict__ dV, float* __restrict__ degE){
  int e = blockIdx.x * blockDim.x + threadIdx.x;
  if (e >= E) return;
  int b = eo[e], en = eo[e + 1];
  float s = 0.f;
  for (int k = b; k < en; k++) s += (float)dV[nodes[k]];
  float cnt = (float)(en - b);
  float dE = s / fmaxf(cnt, 1.0f);
  degE[e] = dE > 0.f ? 1.0f / sqrtf(dE) : 1.0f;
}

// e init: cast e_in -> e0h (linear fp16; doubles as layer-0 ehL) + layer-0 e-scores
__global__ __launch_bounds__(256) void k_einit(const float2* __restrict__ e_in2,
    const float* __restrict__ aw1, const float* __restrict__ aw2,
    int E, __half2* __restrict__ e0h,
    float* __restrict__ se1, float* __restrict__ se2){
  int wave = threadIdx.x >> 6, lane = threadIdx.x & 63;
  int e = blockIdx.x * 4 + wave;
  if (e >= E) return;
  float2 v = e_in2[(size_t)e * 64 + lane];
  e0h[(size_t)e * 64 + lane] = __floats2half2_rn(v.x, v.y);
  float2 a2v = ((const float2*)aw2)[lane];
  float2 a1v = ((const float2*)aw1)[lane];
  float s1 = v.x * a2v.x + v.y * a2v.y;
  float s2 = v.x * a1v.x + v.y * a1v.y;
  s1 = wave_sum(s1); s2 = wave_sum(s2);
  if (lane == 0){ se1[e] = s1; se2[e] = s2; }
}

// transpose-cast weights to fp16 with residual fold (m>=1: beta*W + (1-beta)*I)
__global__ void k_wcast(const float* __restrict__ W0, const float* __restrict__ Wn,
                        const float* __restrict__ We, _Float16* __restrict__ Wt){
  int idx = blockIdx.x * 256 + threadIdx.x;
  if (idx >= 9 * 16384) return;
  int m = idx >> 14, r = idx & 16383;
  int n = r >> 7, k = r & 127;
  float v;
  if (m == 0){
    v = W0[k * 128 + n];
  } else {
    int i = (m <= 4) ? m - 1 : m - 5;
    const float* src = (m <= 4) ? Wn + (size_t)i * 16384 : We + (size_t)i * 16384;
    float beta = logf(0.5f / (float)(i + 1) + 1.0f);
    v = beta * src[k * 128 + n] + ((n == k) ? (1.0f - beta) : 0.f);
  }
  Wt[(size_t)m * 16384 + n * 128 + k] = (_Float16)v;
}

// ---- per-layer kernels ---------------------------------------------------

__device__ inline void acc8h(const float4 q, float w, float* a){
  float2 h0 = __half22float2(*(const __half2*)&q.x);
  float2 h1 = __half22float2(*(const __half2*)&q.y);
  float2 h2v = __half22float2(*(const __half2*)&q.z);
  float2 h3 = __half22float2(*(const __half2*)&q.w);
  a[0] += w * h0.x; a[1] += w * h0.y; a[2] += w * h1.x; a[3] += w * h1.y;
  a[4] += w * h2v.x; a[5] += w * h2v.y; a[6] += w * h3.x; a[7] += w * h3.y;
}

// MERGED v2e softmax + pass1 aggregation. ONE WAVE PER EDGE:
// score phase uses all 64 lanes (2 regs, cap 128); gather uses 4x16-lane
// subgroups with 4 CSR entries in flight. Writes FULL interleaved ET rows.
__global__ __launch_bounds__(256) void k_sma1(
    const int* __restrict__ nodes, const int* __restrict__ eo,
    const float* __restrict__ sx1, const float* __restrict__ se1,
    const float* __restrict__ dist, const float* __restrict__ deg,
    const float* __restrict__ ab, const float* __restrict__ wdw, const float* __restrict__ wdb,
    const float* __restrict__ wgw, const float* __restrict__ wgb, int li,
    const float* __restrict__ degE, const float4* __restrict__ xh4,
    const _Float16* __restrict__ ehL,
    int E, float* __restrict__ a_v2e, float* __restrict__ esc, _Float16* __restrict__ ETraw){
  __shared__ float lw[4][SMAX_CAP];
  int lane = threadIdx.x & 63;
  int wave = threadIdx.x >> 6;
  int e = blockIdx.x * 4 + wave;
  if (e >= E) return;
  int b = eo[e], en = eo[e + 1];
  int l16 = lane & 15, q16 = lane >> 4;
  if (b >= en){
    if (lane == 0) esc[e] = 0.f;
    if (q16 == 0){
      f16x8 ehv = *(const f16x8*)(ehL + (size_t)e * 128 + 8 * l16);
      f16x8 o0, o1;
#pragma unroll
      for (int q = 0; q < 2; q++){
        o0[4 * q] = (_Float16)0.f; o0[4 * q + 1] = (_Float16)0.f;
        o0[4 * q + 2] = ehv[2 * q]; o0[4 * q + 3] = ehv[2 * q + 1];
        o1[4 * q] = (_Float16)0.f; o1[4 * q + 1] = (_Float16)0.f;
        o1[4 * q + 2] = ehv[2 * q + 4]; o1[4 * q + 3] = ehv[2 * q + 5];
      }
      _Float16* dst = ETraw + (size_t)e * 256 + 16 * l16;
      *(f16x8*)dst = o0; *(f16x8*)(dst + 8) = o1;
    }
    return;
  }
  float base = se1[e] + ab[li] + wdb[li] + wgb[li];
  float wd = wdw[li], wg = wgw[li];
  float m = -INFINITY;
  float sreg[2];
#pragma unroll
  for (int c = 0; c < 2; c++){
    int k = b + lane + 64 * c;
    if (k < en){
      float s = sx1[nodes[k]] + base + dist[k] * wd + deg[k] * wg;
      sreg[c] = s; m = fmaxf(m, s);
    }
  }
  for (int k = b + lane + SMAX_CAP; k < en; k += 64){  // statistically never
    float s = sx1[nodes[k]] + base + dist[k] * wd + deg[k] * wg;
    m = fmaxf(m, s);
  }
#pragma unroll
  for (int mm = 32; mm >= 1; mm >>= 1) m = fmaxf(m, __shfl_xor(m, mm, 64));
  float sum = 0.f;
#pragma unroll
  for (int c = 0; c < 2; c++){
    int k = b + lane + 64 * c;
    if (k < en){
      float ex = __expf(sreg[c] - m);
      a_v2e[k] = ex; lw[wave][lane + 64 * c] = ex; sum += ex;
    }
  }
  for (int k = b + lane + SMAX_CAP; k < en; k += 64){  // statistically never
    float s = sx1[nodes[k]] + base + dist[k] * wd + deg[k] * wg;
    float ex = __expf(s - m);
    a_v2e[k] = ex; sum += ex;
  }
#pragma unroll
  for (int mm = 32; mm >= 1; mm >>= 1) sum += __shfl_xor(sum, mm, 64);
  float sc = degE[e] / sum;
  if (lane == 0) esc[e] = sc;
  // gather phase: 4 subgroups of 16 lanes, entries k, k+1, k+2, k+3 in flight
  float a[8] = {0.f, 0.f, 0.f, 0.f, 0.f, 0.f, 0.f, 0.f};
  int k = b + q16;
  for (; k + 4 < en; k += 8){
    float w0 = (k - b < SMAX_CAP) ? lw[wave][k - b] : a_v2e[k];
    float w1 = (k + 4 - b < SMAX_CAP) ? lw[wave][k + 4 - b] : a_v2e[k + 4];
    int n0 = nodes[k], n1 = nodes[k + 4];
    float4 v0 = xh4[(size_t)n0 * 16 + l16];
    float4 v1 = xh4[(size_t)n1 * 16 + l16];
    acc8h(v0, w0, a); acc8h(v1, w1, a);
  }
  for (; k < en; k += 4){
    float w = (k - b < SMAX_CAP) ? lw[wave][k - b] : a_v2e[k];
    int n = nodes[k];
    float4 v = xh4[(size_t)n * 16 + l16];
    acc8h(v, w, a);
  }
#pragma unroll
  for (int j = 0; j < 8; j++){
    a[j] += __shfl_xor(a[j], 16, 64);
    a[j] += __shfl_xor(a[j], 32, 64);
  }
  if (q16 == 0){
    f16x8 ehv = *(const f16x8*)(ehL + (size_t)e * 128 + 8 * l16);
    f16x8 o0, o1;
#pragma unroll
    for (int q = 0; q < 2; q++){
      __half2 xa = __floats2half2_rn(a[2 * q] * sc, a[2 * q + 1] * sc);
      o0[4 * q] = ((_Float16*)&xa)[0]; o0[4 * q + 1] = ((_Float16*)&xa)[1];
      o0[4 * q + 2] = ehv[2 * q]; o0[4 * q + 3] = ehv[2 * q + 1];
      __half2 xb = __floats2half2_rn(a[2 * q + 4] * sc, a[2 * q + 5] * sc);
      o1[4 * q] = ((_Float16*)&xb)[0]; o1[4 * q + 1] = ((_Float16*)&xb)[1];
      o1[4 * q + 2] = ehv[2 * q + 4]; o1[4 * q + 3] = ehv[2 * q + 5];
    }
    _Float16* dst = ETraw + (size_t)e * 256 + 16 * l16;
    *(f16x8*)dst = o0; *(f16x8*)(dst + 8) = o1;
  }
}

__device__ inline void acc8(const float4 q, float w, float* a1, float* a2){
  float2 x0 = __half22float2(*(const __half2*)&q.x);
  float2 e0 = __half22float2(*(const __half2*)&q.y);
  float2 x1 = __half22float2(*(const __half2*)&q.z);
  float2 e1 = __half22float2(*(const __half2*)&q.w);
  a1[0] += w * x0.x; a1[1] += w * x0.y; a1[2] += w * x1.x; a1[3] += w * x1.y;
  a2[0] += w * e0.x; a2[1] += w * e0.y; a2[2] += w * e1.x; a2[3] += w * e1.y;
}

// pass2 FUSED with e2v softmax: 32-lane group per node; 8B packed CSR payload;
// ET gathered as 16B float4 per lane; fast path (deg<=32) with 8-deep prefetch.
// (r7 variant — empirically the best issue structure for this kernel.)
__global__ __launch_bounds__(256) void k_agg2f(
    const float2* __restrict__ pack, const int* __restrict__ no,
    const float* __restrict__ se2, const float* __restrict__ sx2,
    const float* __restrict__ ab, const float* __restrict__ wdw, const float* __restrict__ wdb,
    const float* __restrict__ wgw, const float* __restrict__ wgb, int li,
    const float4* __restrict__ ETq,
    const float* __restrict__ degV, const __half2* __restrict__ x0h,
    int N, __half2* __restrict__ Xv2h, __half2* __restrict__ xiH){
  int l32 = threadIdx.x & 31;
  int grp = threadIdx.x >> 5;
  int n = blockIdx.x * 8 + grp;
  if (n >= N) return;
  int b = no[n], en = no[n + 1];
  float base = sx2[n] + ab[li] + wdb[li] + wgb[li];
  float wd = wdw[li], wg = wgw[li];
  float2 x0v2 = *(const float2*)&x0h[(size_t)n * 64 + 2 * l32];  // prefetch residual
  float l_run = 0.f;
  float a1[4] = {0.f, 0.f, 0.f, 0.f}, a2[4] = {0.f, 0.f, 0.f, 0.f};
  if (en - b <= 32){
    int cs = en - b;
    float s = -INFINITY; int e_l = 0;
    if (l32 < cs){
      float2 pk = pack[b + l32];
      e_l = __float_as_int(pk.x);
      int vi = (int)pk.y;
      s = se2[e_l] + base + (float)(vi & 63) * wd + (float)(vi >> 6) * wg;
    }
    float m_c = s;
#pragma unroll
    for (int mm = 16; mm >= 1; mm >>= 1) m_c = fmaxf(m_c, __shfl_xor(m_c, mm, 32));
    float p = (l32 < cs) ? __expf(s - m_c) : 0.f;
    l_run = p;
#pragma unroll
    for (int mm = 16; mm >= 1; mm >>= 1) l_run += __shfl_xor(l_run, mm, 32);
    int jj = 0;
    for (; jj + 7 < cs; jj += 8){
      float w[8]; int ei[8]; float4 q[8];
#pragma unroll
      for (int u = 0; u < 8; u++){
        w[u] = __shfl(p, jj + u, 32);
        ei[u] = __shfl(e_l, jj + u, 32);
      }
#pragma unroll
      for (int u = 0; u < 8; u++) q[u] = ETq[(size_t)ei[u] * 32 + l32];
#pragma unroll
      for (int u = 0; u < 8; u++) acc8(q[u], w[u], a1, a2);
    }
    for (; jj + 3 < cs; jj += 4){
      float w[4]; int ei[4]; float4 q[4];
#pragma unroll
      for (int u = 0; u < 4; u++){
        w[u] = __shfl(p, jj + u, 32);
        ei[u] = __shfl(e_l, jj + u, 32);
      }
#pragma unroll
      for (int u = 0; u < 4; u++) q[u] = ETq[(size_t)ei[u] * 32 + l32];
#pragma unroll
      for (int u = 0; u < 4; u++) acc8(q[u], w[u], a1, a2);
    }
    for (; jj < cs; jj++){
      float w = __shfl(p, jj, 32);
      int ei_ = __shfl(e_l, jj, 32);
      float4 q = ETq[(size_t)ei_ * 32 + l32];
      acc8(q, w, a1, a2);
    }
  } else {
    float m_run = -INFINITY;
    for (int cb = b; cb < en; cb += 32){
      int cs = min(32, en - cb);
      float s = -INFINITY; int e_l = 0;
      if (l32 < cs){
        float2 pk = pack[cb + l32];
        e_l = __float_as_int(pk.x);
        int vi = (int)pk.y;
        s = se2[e_l] + base + (float)(vi & 63) * wd + (float)(vi >> 6) * wg;
      }
      float m_c = s;
#pragma unroll
      for (int mm = 16; mm >= 1; mm >>= 1) m_c = fmaxf(m_c, __shfl_xor(m_c, mm, 32));
      float p = (l32 < cs) ? __expf(s - m_c) : 0.f;
      float l_c = p;
#pragma unroll
      for (int mm = 16; mm >= 1; mm >>= 1) l_c += __shfl_xor(l_c, mm, 32);
      float m_new = fmaxf(m_run, m_c);
      float f_old = __expf(m_run - m_new);
      float f_c = __expf(m_c - m_new);
#pragma unroll
      for (int r = 0; r < 4; r++){ a1[r] *= f_old; a2[r] *= f_old; }
      l_run = l_run * f_old + l_c * f_c;
      m_run = m_new;
      int jj = 0;
      for (; jj + 3 < cs; jj += 4){
        float w0 = __shfl(p, jj, 32) * f_c;
        float w1 = __shfl(p, jj + 1, 32) * f_c;
        float w2 = __shfl(p, jj + 2, 32) * f_c;
        float w3 = __shfl(p, jj + 3, 32) * f_c;
        int e0i = __shfl(e_l, jj, 32);
        int e1i = __shfl(e_l, jj + 1, 32);
        int e2i = __shfl(e_l, jj + 2, 32);
        int e3i = __shfl(e_l, jj + 3, 32);
        float4 q0 = ETq[(size_t)e0i * 32 + l32];
        float4 q1 = ETq[(size_t)e1i * 32 + l32];
        float4 q2 = ETq[(size_t)e2i * 32 + l32];
        float4 q3 = ETq[(size_t)e3i * 32 + l32];
        acc8(q0, w0, a1, a2);
        acc8(q1, w1, a1, a2);
        acc8(q2, w2, a1, a2);
        acc8(q3, w3, a1, a2);
      }
      for (; jj < cs; jj++){
        float w = __shfl(p, jj, 32) * f_c;
        int ei_ = __shfl(e_l, jj, 32);
        float4 q = ETq[(size_t)ei_ * 32 + l32];
        acc8(q, w, a1, a2);
      }
    }
  }
  float inv = l_run > 0.f ? 1.0f / l_run : 0.f;
  float dv = degV[n] * inv;
  float2 st;
  *(__half2*)&st.x = __floats2half2_rn(a2[0] * dv, a2[1] * dv);
  *(__half2*)&st.y = __floats2half2_rn(a2[2] * dv, a2[3] * dv);
  *(float2*)&Xv2h[(size_t)n * 64 + 2 * l32] = st;
  float2 h0 = __half22float2(*(const __half2*)&x0v2.x);
  float2 h1 = __half22float2(*(const __half2*)&x0v2.y);
  float2 xo;
  *(__half2*)&xo.x = __floats2half2_rn(0.45f * dv * (a1[0] + a2[0]) + 0.1f * h0.x,
                                       0.45f * dv * (a1[1] + a2[1]) + 0.1f * h0.y);
  *(__half2*)&xo.y = __floats2half2_rn(0.45f * dv * (a1[2] + a2[2]) + 0.1f * h1.x,
                                       0.45f * dv * (a1[3] + a2[3]) + 0.1f * h1.y);
  *(float2*)&xiH[(size_t)n * 64 + 2 * l32] = xo;
}

// GEMM body: 4 waves, 64 rows x 128 cols, K=128, fp16 A, residual folded into Wt.
// fp16 outputs staged through LDS for fully-coalesced 256B-row stores.
__device__ __forceinline__ void gemm_body(
    const _Float16* __restrict__ Ah, const _Float16* __restrict__ Wt,
    float* __restrict__ outf, _Float16* __restrict__ outh,
    const float* __restrict__ awA, const float* __restrict__ awB,
    float* __restrict__ sA, float* __restrict__ sB,
    int nrows, int do_relu, int blockRow0, _Float16 (*sh)[136]){
  int lane = threadIdx.x & 63, wave = threadIdx.x >> 6;
  int row0 = blockRow0 + wave * 16;
  int lm = lane & 15;
  int lk8 = (lane >> 4) * 8;
  int rbase = (lane >> 4) * 4;
  if (row0 < nrows){
    int arow = row0 + lm; if (arow >= nrows) arow = nrows - 1;
    f16x8 afrag[4];
#pragma unroll
    for (int ks = 0; ks < 4; ks++)
      afrag[ks] = *(const f16x8*)(Ah + (size_t)arow * 128 + ks * 32 + lk8);
    float da[4] = {0.f, 0.f, 0.f, 0.f}, db[4] = {0.f, 0.f, 0.f, 0.f};
    for (int t = 0; t < 8; t++){
      f32x4 acc = {0.f, 0.f, 0.f, 0.f};
#pragma unroll
      for (int ks = 0; ks < 4; ks++){
        f16x8 bf = *(const f16x8*)(Wt + (size_t)(t * 16 + lm) * 128 + ks * 32 + lk8);
        acc = __builtin_amdgcn_mfma_f32_16x16x32_f16(afrag[ks], bf, acc, 0, 0, 0);
      }
      int col = t * 16 + lm;
      float wa = 0.f, wb = 0.f;
      if (awA){ wa = awA[col]; wb = awB[col]; }
#pragma unroll
      for (int r = 0; r < 4; r++){
        int gr = row0 + rbase + r;
        float v = acc[r];
        if (do_relu) v = fmaxf(v, 0.f);
        if (outf && gr < nrows) outf[(size_t)gr * 128 + col] = v;
        if (outh) sh[wave * 16 + rbase + r][col] = (_Float16)v;
        if (gr < nrows){ da[r] += v * wa; db[r] += v * wb; }
      }
    }
    if (awA){
#pragma unroll
      for (int r = 0; r < 4; r++){
        float a = da[r], bb = db[r];
#pragma unroll
        for (int m = 8; m >= 1; m >>= 1){
          a += __shfl_xor(a, m, 64);
          bb += __shfl_xor(bb, m, 64);
        }
        int gr = row0 + rbase + r;
        if (lm == 0 && gr < nrows){ sA[gr] = a; sB[gr] = bb; }
      }
    }
  }
  if (outh){
    __syncthreads();
    for (int i = threadIdx.x; i < 64 * 16; i += 256){
      int rr = i >> 4, cc = (i & 15) * 8;
      int gr = blockRow0 + rr;
      if (gr < nrows)
        *(f16x8*)(outh + (size_t)gr * 128 + cc) = *(const f16x8*)&sh[rr][cc];
    }
  }
}

// MERGED agg3 || x-GEMM, STRIPED 3:1 so resident windows hold both kinds.
// agg3: wave per edge, 4x16-lane subgroups. x-GEMM: gemm_body with LDS epilogue.
__global__ __launch_bounds__(256) void k_a3gx(
    const int* __restrict__ nodes, const int* __restrict__ eo,
    const float4* __restrict__ Xv2h4, const float* __restrict__ a_v2e,
    const float* __restrict__ esc,
    const float4* __restrict__ ETq, const float4* __restrict__ e0h4,
    int E, __half2* __restrict__ eiH, int nbx,
    const _Float16* __restrict__ Ah, const _Float16* __restrict__ Wt,
    float* __restrict__ outf, _Float16* __restrict__ outh,
    const float* __restrict__ awA, const float* __restrict__ awB,
    float* __restrict__ sA, float* __restrict__ sB, int N, int do_relu){
  __shared__ _Float16 sh[64][136];
  int g = blockIdx.x;
  int k4 = g >> 2, r4 = g & 3;
  bool isx = (r4 == 3) && (k4 < nbx);
  if (isx){
    gemm_body(Ah, Wt, outf, outh, awA, awB, sA, sB, N, do_relu, k4 * 64, sh);
    return;
  }
  int axi = g - min(k4 + (r4 == 3 ? 1 : 0), nbx);
  int lane = threadIdx.x & 63;
  int wave = threadIdx.x >> 6;
  int e = axi * 4 + wave;
  if (e >= E) return;
  int b = eo[e], en = eo[e + 1];
  int l16 = lane & 15, q16 = lane >> 4;
  float a[8] = {0.f, 0.f, 0.f, 0.f, 0.f, 0.f, 0.f, 0.f};
  int k = b + q16;
  for (; k + 4 < en; k += 8){
    float w0 = a_v2e[k], w1 = a_v2e[k + 4];
    int n0 = nodes[k], n1 = nodes[k + 4];
    float4 v0 = Xv2h4[(size_t)n0 * 16 + l16];
    float4 v1 = Xv2h4[(size_t)n1 * 16 + l16];
    acc8h(v0, w0, a); acc8h(v1, w1, a);
  }
  for (; k < en; k += 4){
    float w = a_v2e[k];
    int n = nodes[k];
    float4 v = Xv2h4[(size_t)n * 16 + l16];
    acc8h(v, w, a);
  }
#pragma unroll
  for (int j = 0; j < 8; j++){
    a[j] += __shfl_xor(a[j], 16, 64);
    a[j] += __shfl_xor(a[j], 32, 64);
  }
  if (q16 == 0){
    float dE = esc[e];
    float4 q0 = ETq[(size_t)e * 32 + 2 * l16];
    float4 q1 = ETq[(size_t)e * 32 + 2 * l16 + 1];
    float2 x01 = __half22float2(*(const __half2*)&q0.x);
    float2 x23 = __half22float2(*(const __half2*)&q0.z);
    float2 x45 = __half22float2(*(const __half2*)&q1.x);
    float2 x67 = __half22float2(*(const __half2*)&q1.z);
    float4 ev = e0h4[(size_t)e * 16 + l16];
    float2 g0 = __half22float2(*(const __half2*)&ev.x);
    float2 g1 = __half22float2(*(const __half2*)&ev.y);
    float2 g2 = __half22float2(*(const __half2*)&ev.z);
    float2 g3 = __half22float2(*(const __half2*)&ev.w);
    float4 o;
    *(__half2*)&o.x = __floats2half2_rn(0.45f * (x01.x + a[0] * dE) + 0.1f * g0.x,
                                        0.45f * (x01.y + a[1] * dE) + 0.1f * g0.y);
    *(__half2*)&o.y = __floats2half2_rn(0.45f * (x23.x + a[2] * dE) + 0.1f * g1.x,
                                        0.45f * (x23.y + a[3] * dE) + 0.1f * g1.y);
    *(__half2*)&o.z = __floats2half2_rn(0.45f * (x45.x + a[4] * dE) + 0.1f * g2.x,
                                        0.45f * (x45.y + a[5] * dE) + 0.1f * g2.y);
    *(__half2*)&o.w = __floats2half2_rn(0.45f * (x67.x + a[6] * dE) + 0.1f * g3.x,
                                        0.45f * (x67.y + a[7] * dE) + 0.1f * g3.y);
    *(float4*)&eiH[(size_t)e * 64 + 4 * l16] = o;
  }
}

// standalone e-GEMM (linear fp16 ehL out, or f32 out_e at i=3)
__global__ __launch_bounds__(256) void k_gemme(
    const _Float16* __restrict__ Ah, const _Float16* __restrict__ Wt,
    float* __restrict__ outf, _Float16* __restrict__ outh,
    const float* __restrict__ awA, const float* __restrict__ awB,
    float* __restrict__ sA, float* __restrict__ sB, int nrows, int do_relu){
  __shared__ _Float16 sh[64][136];
  gemm_body(Ah, Wt, outf, outh, awA, awB, sA, sB, nrows, do_relu,
            blockIdx.x * 64, sh);
}

// initial GEMM: A built from f32 x_in; out = relu(acc + bias); LDS-staged stores to
// xh AND x0h (both linear fp16); fused layer-0 x-scores.
__global__ __launch_bounds__(256) void k_gemm0(
    const float* __restrict__ Af, const _Float16* __restrict__ Wt,
    const float* __restrict__ bias,
    _Float16* __restrict__ outh, _Float16* __restrict__ outh2,
    const float* __restrict__ awA, const float* __restrict__ awB,
    float* __restrict__ sA, float* __restrict__ sB, int nrows){
  __shared__ _Float16 sh[64][136];
  int wave = threadIdx.x >> 6, lane = threadIdx.x & 63;
  int blockRow0 = blockIdx.x * 64;
  int row0 = blockRow0 + wave * 16;
  int lm = lane & 15;
  int lk8 = (lane >> 4) * 8;
  int rbase = (lane >> 4) * 4;
  if (row0 < nrows){
    int arow = row0 + lm; if (arow >= nrows) arow = nrows - 1;
    const float* ap = Af + (size_t)arow * 128;
    f16x8 afrag[4];
#pragma unroll
    for (int ks = 0; ks < 4; ks++){
      float4 v0 = *(const float4*)(ap + ks * 32 + lk8);
      float4 v1 = *(const float4*)(ap + ks * 32 + lk8 + 4);
      f16x8 a;
      a[0] = (_Float16)v0.x; a[1] = (_Float16)v0.y; a[2] = (_Float16)v0.z; a[3] = (_Float16)v0.w;
      a[4] = (_Float16)v1.x; a[5] = (_Float16)v1.y; a[6] = (_Float16)v1.z; a[7] = (_Float16)v1.w;
      afrag[ks] = a;
    }
    float da[4] = {0.f, 0.f, 0.f, 0.f}, db[4] = {0.f, 0.f, 0.f, 0.f};
    for (int t = 0; t < 8; t++){
      f32x4 acc = {0.f, 0.f, 0.f, 0.f};
#pragma unroll
      for (int ks = 0; ks < 4; ks++){
        f16x8 bf = *(const f16x8*)(Wt + (size_t)(t * 16 + lm) * 128 + ks * 32 + lk8);
        acc = __builtin_amdgcn_mfma_f32_16x16x32_f16(afrag[ks], bf, acc, 0, 0, 0);
      }
      int col = t * 16 + lm;
      float wa = awA[col], wb = awB[col];
      float bi = bias[col];
#pragma unroll
      for (int r = 0; r < 4; r++){
        int gr = row0 + rbase + r;
        float v = fmaxf(acc[r] + bi, 0.f);
        sh[wave * 16 + rbase + r][col] = (_Float16)v;
        if (gr < nrows){ da[r] += v * wa; db[r] += v * wb; }
      }
    }
#pragma unroll
    for (int r = 0; r < 4; r++){
      float a = da[r], bb = db[r];
#pragma unroll
      for (int m = 8; m >= 1; m >>= 1){
        a += __shfl_xor(a, m, 64);
        bb += __shfl_xor(bb, m, 64);
      }
      int gr = row0 + rbase + r;
      if (lm == 0 && gr < nrows){ sA[gr] = a; sB[gr] = bb; }
    }
  }
  __syncthreads();
  for (int i = threadIdx.x; i < 64 * 16; i += 256){
    int rr = i >> 4, cc = (i & 15) * 8;
    int gr = blockRow0 + rr;
    if (gr < nrows){
      f16x8 v = *(const f16x8*)&sh[rr][cc];
      *(f16x8*)(outh + (size_t)gr * 128 + cc) = v;
      *(f16x8*)(outh2 + (size_t)gr * 128 + cc) = v;
    }
  }
}

// ---- host ----------------------------------------------------------------

extern "C" void kernel_launch(void* const* d_in, const int* in_sizes, int n_in,
                              void* d_out, int out_size, void* d_ws, size_t ws_size,
                              hipStream_t stream) {
  const float* x_in     = (const float*)d_in[0];
  const float* e_in     = (const float*)d_in[1];
  const int*   hei      = (const int*)d_in[2];
  const float* dist_v2e = (const float*)d_in[3];
  const float* deg_v2e  = (const float*)d_in[4];
  const float* dist_e2v = (const float*)d_in[5];
  const float* deg_e2v  = (const float*)d_in[6];
  const float* W0       = (const float*)d_in[7];
  const float* b0       = (const float*)d_in[8];
  const float* Wn       = (const float*)d_in[9];
  const float* We       = (const float*)d_in[10];
  const float* attn_w   = (const float*)d_in[11];
  const float* attn_b   = (const float*)d_in[12];
  const float* wd_w     = (const float*)d_in[13];
  const float* wd_b     = (const float*)d_in[14];
  const float* wg_w     = (const float*)d_in[15];
  const float* wg_b     = (const float*)d_in[16];

  const int N   = in_sizes[0] / DD;
  const int E   = in_sizes[1] / DD;
  const int NNZ = in_sizes[2] / 2;
  const int* nodesArr = hei;
  const int* edgesArr = hei + NNZ;

  float* out_x = (float*)d_out;
  float* out_e = (float*)d_out + (size_t)N * DD;

  // aliases inside d_out (fully overwritten by final GEMMs):
  // x-region second half: xh (fp16). e-region: ET interleaved table (E x 512B).
  __half2* xh   = (__half2*)((char*)out_x + (size_t)N * DD * 2);
  _Float16* ETraw = (_Float16*)out_e;
  const float4* ETq = (const float4*)out_e;

  char* wsp = (char*)d_ws;
  auto alloc = [&](size_t bytes) -> void* {
    void* p = (void*)wsp;
    wsp += (bytes + 255) / 256 * 256;
    return p;
  };
  _Float16* x0h  = (_Float16*)alloc((size_t)N * DD * 2);  // x0 residual, fp16
  _Float16* Xv2h = (_Float16*)alloc((size_t)N * DD * 2);  // Xv2, fp16
  _Float16* xiH  = (_Float16*)alloc((size_t)N * DD * 2);  // xi, fp16
  _Float16* eiH  = (_Float16*)alloc((size_t)E * DD * 2);  // ei, fp16
  _Float16* e0h  = (_Float16*)alloc((size_t)E * DD * 2);  // e0 residual (= layer-0 ehL)
  _Float16* ehL  = (_Float16*)alloc((size_t)E * DD * 2);  // eh linear (layers 1..3)
  _Float16* Wt   = (_Float16*)alloc((size_t)9 * 16384 * 2);
  float* sx1   = (float*)alloc((size_t)N * 4);
  float* sx2   = (float*)alloc((size_t)N * 4);
  float* se1   = (float*)alloc((size_t)E * 4);
  float* se2   = (float*)alloc((size_t)E * 4);
  float* a_v2e = (float*)alloc((size_t)NNZ * 4);
  float* degV  = (float*)alloc((size_t)N * 4);
  float* degE  = (float*)alloc((size_t)E * 4);
  float* esc   = (float*)alloc((size_t)E * 4);
  float2* pack = (float2*)alloc((size_t)NNZ * 8);
  int* dV_i  = (int*)alloc((size_t)N * 4);
  int* no_   = (int*)alloc((size_t)(N + 1) * 4);
  int* nfill = (int*)alloc((size_t)N * 4);
  int* eo    = (int*)alloc((size_t)(E + 1) * 4);
  int* part  = (int*)alloc((size_t)SCAN_BLOCKS * 4);

  // ---- setup
  hipMemsetAsync(dV_i, 0, (size_t)N * 4, stream);
  k_edge_offsets<<<(E + 1 + 255) / 256, 256, 0, stream>>>(edgesArr, NNZ, E, eo);
  k_hist<<<(NNZ + 255) / 256, 256, 0, stream>>>(nodesArr, NNZ, dV_i);
  k_scan_partial<<<SCAN_BLOCKS, 256, 0, stream>>>(dV_i, N, part);
  k_scan_blocksums<<<1, SCAN_BLOCKS, 0, stream>>>(part);
  k_scan_apply<<<SCAN_BLOCKS, 256, 0, stream>>>(dV_i, N, NNZ, part, no_, nfill, degV);
  k_permpack<<<(NNZ + 255) / 256, 256, 0, stream>>>(nodesArr, edgesArr, dist_e2v, deg_e2v,
                                                    NNZ, nfill, pack);
  k_edge_deg<<<(E + 255) / 256, 256, 0, stream>>>(nodesArr, eo, E, dV_i, degE);
  k_wcast<<<(9 * 16384 + 255) / 256, 256, 0, stream>>>(W0, Wn, We, Wt);

  const float* aw1_0 = attn_w;          // aw[0,:d]
  const float* aw2_0 = attn_w + 128;    // aw[0,d:]

  // e0h (linear fp16 e_in) + layer-0 e-scores
  k_einit<<<(E + 3) / 4, 256, 0, stream>>>((const float2*)e_in, aw1_0, aw2_0,
                                            E, (__half2*)e0h, se1, se2);

  // x0 = relu(x_in @ W0 + b0): LDS-staged coalesced fp16 stores to xh, x0h; scores
  k_gemm0<<<(N + 63) / 64, 256, 0, stream>>>(x_in, Wt, b0,
      (_Float16*)xh, x0h, aw1_0, aw2_0, sx1, sx2, N);

  const int nbx = (N + 63) / 64, nbe = (E + 63) / 64, nbA = (E + 3) / 4;
  for (int i = 0; i < 4; i++){
    const float* aw1n = (i < 3) ? attn_w + (size_t)(i + 1) * 256        : nullptr;
    const float* aw2n = (i < 3) ? attn_w + (size_t)(i + 1) * 256 + 128  : nullptr;
    const _Float16* ehCur = (i == 0) ? e0h : ehL;

    // merged v2e softmax + pass1; writes FULL interleaved ET rows (Xe1 + eh)
    k_sma1<<<(E + 3) / 4, 256, 0, stream>>>(nodesArr, eo, sx1, se1,
        dist_v2e, deg_v2e, attn_b, wd_w, wd_b, wg_w, wg_b, i, degE,
        (const float4*)xh, ehCur, E, a_v2e, esc, ETraw);

    // e2v softmax + node aggregation
    k_agg2f<<<(N + 7) / 8, 256, 0, stream>>>(pack, no_, se2, sx2,
        attn_b, wd_w, wd_b, wg_w, wg_b, i,
        ETq, degV, (const __half2*)x0h, N, (__half2*)Xv2h, (__half2*)xiH);

    // agg3 || x-GEMM, striped 3:1 for true co-residency
    k_a3gx<<<nbA + nbx, 256, 0, stream>>>(
        nodesArr, eo, (const float4*)Xv2h, a_v2e, esc, ETq, (const float4*)e0h,
        E, (__half2*)eiH, nbx,
        xiH, Wt + (size_t)(1 + i) * 16384,
        (i == 3) ? out_x : nullptr, (i < 3) ? (_Float16*)xh : nullptr,
        aw1n, aw2n, sx1, sx2, N, i < 3 ? 1 : 0);

    // e-GEMM
    k_gemme<<<nbe, 256, 0, stream>>>(eiH, Wt + (size_t)(5 + i) * 16384,
        (i == 3) ? out_e : nullptr, (i < 3) ? ehL : nullptr,
        aw2n, aw1n, se1, se2, E, i < 3 ? 1 : 0);
  }
}

// Round 11
// 817.075 us; speedup vs baseline: 1.2890x; 1.2890x over previous
//
#include <hip/hip_runtime.h>
#include <hip/hip_fp16.h>
#include <math.h>

#define DD 128
#define SCAN_BLOCKS 256
#define SMAX_CAP 128

typedef _Float16 f16x8 __attribute__((ext_vector_type(8)));
typedef float f32x4 __attribute__((ext_vector_type(4)));

__device__ inline float wave_sum(float v){
#pragma unroll
  for (int m = 32; m >= 1; m >>= 1) v += __shfl_xor(v, m, 64);
  return v;
}
__device__ inline int wave_sum_i(int v){
#pragma unroll
  for (int m = 32; m >= 1; m >>= 1) v += __shfl_xor(v, m, 64);
  return v;
}

// ---- setup kernels -------------------------------------------------------

__global__ void k_edge_offsets(const int* __restrict__ edges, int nnz, int E,
                               int* __restrict__ eo){
  int e = blockIdx.x * blockDim.x + threadIdx.x;
  if (e > E) return;
  int lo = 0, hi = nnz;
  while (lo < hi){ int mid = (lo + hi) >> 1; if (edges[mid] < e) lo = mid + 1; else hi = mid; }
  eo[e] = lo;
}

__global__ void k_hist(const int* __restrict__ nodes, int nnz, int* __restrict__ dV){
  int k = blockIdx.x * blockDim.x + threadIdx.x;
  if (k < nnz) atomicAdd(&dV[nodes[k]], 1);
}

__global__ __launch_bounds__(256) void k_scan_partial(const int* __restrict__ dV, int N,
                                                      int* __restrict__ part){
  int b = blockIdx.x, t = threadIdx.x;
  int chunk = (N + SCAN_BLOCKS - 1) / SCAN_BLOCKS;
  int s0 = b * chunk, s1 = min(s0 + chunk, N);
  int sum = 0;
  for (int n = s0 + t; n < s1; n += 256) sum += dV[n];
  sum = wave_sum_i(sum);
  __shared__ int wred[4];
  int lane = t & 63, wid = t >> 6;
  if (lane == 0) wred[wid] = sum;
  __syncthreads();
  if (t == 0) part[b] = wred[0] + wred[1] + wred[2] + wred[3];
}

__global__ __launch_bounds__(SCAN_BLOCKS) void k_scan_blocksums(int* __restrict__ part){
  __shared__ int sh[SCAN_BLOCKS];
  int t = threadIdx.x;
  int v = part[t];
  sh[t] = v; __syncthreads();
  for (int off = 1; off < SCAN_BLOCKS; off <<= 1){
    int add = (t >= off) ? sh[t - off] : 0;
    __syncthreads();
    sh[t] += add;
    __syncthreads();
  }
  part[t] = sh[t] - v;
}

__global__ __launch_bounds__(256) void k_scan_apply(const int* __restrict__ dV, int N, int nnz,
    const int* __restrict__ partScan, int* __restrict__ no, int* __restrict__ nfill,
    float* __restrict__ degV){
  int b = blockIdx.x, t = threadIdx.x;
  int chunk = (N + SCAN_BLOCKS - 1) / SCAN_BLOCKS;
  int s0 = b * chunk, s1 = min(s0 + chunk, N);
  int lane = t & 63, wid = t >> 6;
  __shared__ int wtot[4];
  __shared__ int s_run;
  if (t == 0) s_run = partScan[b];
  __syncthreads();
  for (int base = s0; base < s1; base += 256){
    int n = base + t;
    int d = (n < s1) ? dV[n] : 0;
    int v = d;
#pragma unroll
    for (int off = 1; off < 64; off <<= 1){
      int o = __shfl_up(v, off, 64);
      if (lane >= off) v += o;
    }
    if (lane == 63) wtot[wid] = v;
    __syncthreads();
    int run0 = s_run;
    int woff = 0;
    for (int w = 0; w < wid; w++) woff += wtot[w];
    if (n < s1){
      int excl = run0 + woff + v - d;
      no[n] = excl; nfill[n] = excl;
      degV[n] = d > 0 ? 1.0f / sqrtf((float)d) : 1.0f;
    }
    int btot = wtot[0] + wtot[1] + wtot[2] + wtot[3];
    __syncthreads();
    if (t == 0) s_run = run0 + btot;
    __syncthreads();
  }
  if (b == 0 && t == 0) no[N] = nnz;
}

// merged perm+pack: scatter CSR payload directly
__global__ void k_permpack(const int* __restrict__ nodes, const int* __restrict__ edges,
                           const float* __restrict__ dist, const float* __restrict__ deg,
                           int nnz, int* __restrict__ nfill, float2* __restrict__ pack){
  int k = blockIdx.x * blockDim.x + threadIdx.x;
  if (k < nnz){
    int pos = atomicAdd(&nfill[nodes[k]], 1);
    pack[pos] = make_float2(__int_as_float(edges[k]), dist[k] + 64.f * deg[k]);
  }
}

__global__ void k_edge_deg(const int* __restrict__ nodes, const int* __restrict__ eo, int E,
                           const int* __restrict__ dV, float* __restrict__ degE){
  int e = blockIdx.x * blockDim.x + threadIdx.x;
  if (e >= E) return;
  int b = eo[e], en = eo[e + 1];
  float s = 0.f;
  for (int k = b; k < en; k++) s += (float)dV[nodes[k]];
  float cnt = (float)(en - b);
  float dE = s / fmaxf(cnt, 1.0f);
  degE[e] = dE > 0.f ? 1.0f / sqrtf(dE) : 1.0f;
}

// e init: cast e_in -> e0h (linear fp16; doubles as layer-0 ehL) + layer-0 e-scores
__global__ __launch_bounds__(256) void k_einit(const float2* __restrict__ e_in2,
    const float* __restrict__ aw1, const float* __restrict__ aw2,
    int E, __half2* __restrict__ e0h,
    float* __restrict__ se1, float* __restrict__ se2){
  int wave = threadIdx.x >> 6, lane = threadIdx.x & 63;
  int e = blockIdx.x * 4 + wave;
  if (e >= E) return;
  float2 v = e_in2[(size_t)e * 64 + lane];
  e0h[(size_t)e * 64 + lane] = __floats2half2_rn(v.x, v.y);
  float2 a2v = ((const float2*)aw2)[lane];
  float2 a1v = ((const float2*)aw1)[lane];
  float s1 = v.x * a2v.x + v.y * a2v.y;
  float s2 = v.x * a1v.x + v.y * a1v.y;
  s1 = wave_sum(s1); s2 = wave_sum(s2);
  if (lane == 0){ se1[e] = s1; se2[e] = s2; }
}

// transpose-cast weights to fp16 with residual fold (m>=1: beta*W + (1-beta)*I)
__global__ void k_wcast(const float* __restrict__ W0, const float* __restrict__ Wn,
                        const float* __restrict__ We, _Float16* __restrict__ Wt){
  int idx = blockIdx.x * 256 + threadIdx.x;
  if (idx >= 9 * 16384) return;
  int m = idx >> 14, r = idx & 16383;
  int n = r >> 7, k = r & 127;
  float v;
  if (m == 0){
    v = W0[k * 128 + n];
  } else {
    int i = (m <= 4) ? m - 1 : m - 5;
    const float* src = (m <= 4) ? Wn + (size_t)i * 16384 : We + (size_t)i * 16384;
    float beta = logf(0.5f / (float)(i + 1) + 1.0f);
    v = beta * src[k * 128 + n] + ((n == k) ? (1.0f - beta) : 0.f);
  }
  Wt[(size_t)m * 16384 + n * 128 + k] = (_Float16)v;
}

// ---- per-layer kernels ---------------------------------------------------

__device__ inline void acc8h(const float4 q, float w, float* a){
  float2 h0 = __half22float2(*(const __half2*)&q.x);
  float2 h1 = __half22float2(*(const __half2*)&q.y);
  float2 h2v = __half22float2(*(const __half2*)&q.z);
  float2 h3 = __half22float2(*(const __half2*)&q.w);
  a[0] += w * h0.x; a[1] += w * h0.y; a[2] += w * h1.x; a[3] += w * h1.y;
  a[4] += w * h2v.x; a[5] += w * h2v.y; a[6] += w * h3.x; a[7] += w * h3.y;
}

// MERGED v2e softmax + pass1 aggregation. ONE WAVE PER EDGE:
// score phase uses all 64 lanes (2 regs, cap 128); gather uses 4x16-lane
// subgroups with 4 CSR entries in flight. Writes FULL interleaved ET rows.
__global__ __launch_bounds__(256) void k_sma1(
    const int* __restrict__ nodes, const int* __restrict__ eo,
    const float* __restrict__ sx1, const float* __restrict__ se1,
    const float* __restrict__ dist, const float* __restrict__ deg,
    const float* __restrict__ ab, const float* __restrict__ wdw, const float* __restrict__ wdb,
    const float* __restrict__ wgw, const float* __restrict__ wgb, int li,
    const float* __restrict__ degE, const float4* __restrict__ xh4,
    const _Float16* __restrict__ ehL,
    int E, float* __restrict__ a_v2e, float* __restrict__ esc, _Float16* __restrict__ ETraw){
  __shared__ float lw[4][SMAX_CAP];
  int lane = threadIdx.x & 63;
  int wave = threadIdx.x >> 6;
  int e = blockIdx.x * 4 + wave;
  if (e >= E) return;
  int b = eo[e], en = eo[e + 1];
  int l16 = lane & 15, q16 = lane >> 4;
  if (b >= en){
    if (lane == 0) esc[e] = 0.f;
    if (q16 == 0){
      f16x8 ehv = *(const f16x8*)(ehL + (size_t)e * 128 + 8 * l16);
      f16x8 o0, o1;
#pragma unroll
      for (int q = 0; q < 2; q++){
        o0[4 * q] = (_Float16)0.f; o0[4 * q + 1] = (_Float16)0.f;
        o0[4 * q + 2] = ehv[2 * q]; o0[4 * q + 3] = ehv[2 * q + 1];
        o1[4 * q] = (_Float16)0.f; o1[4 * q + 1] = (_Float16)0.f;
        o1[4 * q + 2] = ehv[2 * q + 4]; o1[4 * q + 3] = ehv[2 * q + 5];
      }
      _Float16* dst = ETraw + (size_t)e * 256 + 16 * l16;
      *(f16x8*)dst = o0; *(f16x8*)(dst + 8) = o1;
    }
    return;
  }
  float base = se1[e] + ab[li] + wdb[li] + wgb[li];
  float wd = wdw[li], wg = wgw[li];
  float m = -INFINITY;
  float sreg[2];
#pragma unroll
  for (int c = 0; c < 2; c++){
    int k = b + lane + 64 * c;
    if (k < en){
      float s = sx1[nodes[k]] + base + dist[k] * wd + deg[k] * wg;
      sreg[c] = s; m = fmaxf(m, s);
    }
  }
  for (int k = b + lane + SMAX_CAP; k < en; k += 64){  // statistically never
    float s = sx1[nodes[k]] + base + dist[k] * wd + deg[k] * wg;
    m = fmaxf(m, s);
  }
#pragma unroll
  for (int mm = 32; mm >= 1; mm >>= 1) m = fmaxf(m, __shfl_xor(m, mm, 64));
  float sum = 0.f;
#pragma unroll
  for (int c = 0; c < 2; c++){
    int k = b + lane + 64 * c;
    if (k < en){
      float ex = __expf(sreg[c] - m);
      a_v2e[k] = ex; lw[wave][lane + 64 * c] = ex; sum += ex;
    }
  }
  for (int k = b + lane + SMAX_CAP; k < en; k += 64){  // statistically never
    float s = sx1[nodes[k]] + base + dist[k] * wd + deg[k] * wg;
    float ex = __expf(s - m);
    a_v2e[k] = ex; sum += ex;
  }
#pragma unroll
  for (int mm = 32; mm >= 1; mm >>= 1) sum += __shfl_xor(sum, mm, 64);
  float sc = degE[e] / sum;
  if (lane == 0) esc[e] = sc;
  // gather phase: 4 subgroups of 16 lanes, entries k, k+1, k+2, k+3 in flight
  float a[8] = {0.f, 0.f, 0.f, 0.f, 0.f, 0.f, 0.f, 0.f};
  int k = b + q16;
  for (; k + 4 < en; k += 8){
    float w0 = (k - b < SMAX_CAP) ? lw[wave][k - b] : a_v2e[k];
    float w1 = (k + 4 - b < SMAX_CAP) ? lw[wave][k + 4 - b] : a_v2e[k + 4];
    int n0 = nodes[k], n1 = nodes[k + 4];
    float4 v0 = xh4[(size_t)n0 * 16 + l16];
    float4 v1 = xh4[(size_t)n1 * 16 + l16];
    acc8h(v0, w0, a); acc8h(v1, w1, a);
  }
  for (; k < en; k += 4){
    float w = (k - b < SMAX_CAP) ? lw[wave][k - b] : a_v2e[k];
    int n = nodes[k];
    float4 v = xh4[(size_t)n * 16 + l16];
    acc8h(v, w, a);
  }
#pragma unroll
  for (int j = 0; j < 8; j++){
    a[j] += __shfl_xor(a[j], 16, 64);
    a[j] += __shfl_xor(a[j], 32, 64);
  }
  if (q16 == 0){
    f16x8 ehv = *(const f16x8*)(ehL + (size_t)e * 128 + 8 * l16);
    f16x8 o0, o1;
#pragma unroll
    for (int q = 0; q < 2; q++){
      __half2 xa = __floats2half2_rn(a[2 * q] * sc, a[2 * q + 1] * sc);
      o0[4 * q] = ((_Float16*)&xa)[0]; o0[4 * q + 1] = ((_Float16*)&xa)[1];
      o0[4 * q + 2] = ehv[2 * q]; o0[4 * q + 3] = ehv[2 * q + 1];
      __half2 xb = __floats2half2_rn(a[2 * q + 4] * sc, a[2 * q + 5] * sc);
      o1[4 * q] = ((_Float16*)&xb)[0]; o1[4 * q + 1] = ((_Float16*)&xb)[1];
      o1[4 * q + 2] = ehv[2 * q + 4]; o1[4 * q + 3] = ehv[2 * q + 5];
    }
    _Float16* dst = ETraw + (size_t)e * 256 + 16 * l16;
    *(f16x8*)dst = o0; *(f16x8*)(dst + 8) = o1;
  }
}

__device__ inline void acc8(const float4 q, float w, float* a1, float* a2){
  float2 x0 = __half22float2(*(const __half2*)&q.x);
  float2 e0 = __half22float2(*(const __half2*)&q.y);
  float2 x1 = __half22float2(*(const __half2*)&q.z);
  float2 e1 = __half22float2(*(const __half2*)&q.w);
  a1[0] += w * x0.x; a1[1] += w * x0.y; a1[2] += w * x1.x; a1[3] += w * x1.y;
  a2[0] += w * e0.x; a2[1] += w * e0.y; a2[2] += w * e1.x; a2[3] += w * e1.y;
}

// pass2 FUSED with e2v softmax: 32-lane group per node; 8B packed CSR payload;
// ET gathered as 16B float4 per lane; fast path (deg<=32) with 8-deep prefetch.
// (r7 variant — empirically the best issue structure for this kernel.)
__global__ __launch_bounds__(256) void k_agg2f(
    const float2* __restrict__ pack, const int* __restrict__ no,
    const float* __restrict__ se2, const float* __restrict__ sx2,
    const float* __restrict__ ab, const float* __restrict__ wdw, const float* __restrict__ wdb,
    const float* __restrict__ wgw, const float* __restrict__ wgb, int li,
    const float4* __restrict__ ETq,
    const float* __restrict__ degV, const __half2* __restrict__ x0h,
    int N, __half2* __restrict__ Xv2h, __half2* __restrict__ xiH){
  int l32 = threadIdx.x & 31;
  int grp = threadIdx.x >> 5;
  int n = blockIdx.x * 8 + grp;
  if (n >= N) return;
  int b = no[n], en = no[n + 1];
  float base = sx2[n] + ab[li] + wdb[li] + wgb[li];
  float wd = wdw[li], wg = wgw[li];
  float2 x0v2 = *(const float2*)&x0h[(size_t)n * 64 + 2 * l32];  // prefetch residual
  float l_run = 0.f;
  float a1[4] = {0.f, 0.f, 0.f, 0.f}, a2[4] = {0.f, 0.f, 0.f, 0.f};
  if (en - b <= 32){
    int cs = en - b;
    float s = -INFINITY; int e_l = 0;
    if (l32 < cs){
      float2 pk = pack[b + l32];
      e_l = __float_as_int(pk.x);
      int vi = (int)pk.y;
      s = se2[e_l] + base + (float)(vi & 63) * wd + (float)(vi >> 6) * wg;
    }
    float m_c = s;
#pragma unroll
    for (int mm = 16; mm >= 1; mm >>= 1) m_c = fmaxf(m_c, __shfl_xor(m_c, mm, 32));
    float p = (l32 < cs) ? __expf(s - m_c) : 0.f;
    l_run = p;
#pragma unroll
    for (int mm = 16; mm >= 1; mm >>= 1) l_run += __shfl_xor(l_run, mm, 32);
    int jj = 0;
    for (; jj + 7 < cs; jj += 8){
      float w[8]; int ei[8]; float4 q[8];
#pragma unroll
      for (int u = 0; u < 8; u++){
        w[u] = __shfl(p, jj + u, 32);
        ei[u] = __shfl(e_l, jj + u, 32);
      }
#pragma unroll
      for (int u = 0; u < 8; u++) q[u] = ETq[(size_t)ei[u] * 32 + l32];
#pragma unroll
      for (int u = 0; u < 8; u++) acc8(q[u], w[u], a1, a2);
    }
    for (; jj + 3 < cs; jj += 4){
      float w[4]; int ei[4]; float4 q[4];
#pragma unroll
      for (int u = 0; u < 4; u++){
        w[u] = __shfl(p, jj + u, 32);
        ei[u] = __shfl(e_l, jj + u, 32);
      }
#pragma unroll
      for (int u = 0; u < 4; u++) q[u] = ETq[(size_t)ei[u] * 32 + l32];
#pragma unroll
      for (int u = 0; u < 4; u++) acc8(q[u], w[u], a1, a2);
    }
    for (; jj < cs; jj++){
      float w = __shfl(p, jj, 32);
      int ei_ = __shfl(e_l, jj, 32);
      float4 q = ETq[(size_t)ei_ * 32 + l32];
      acc8(q, w, a1, a2);
    }
  } else {
    float m_run = -INFINITY;
    for (int cb = b; cb < en; cb += 32){
      int cs = min(32, en - cb);
      float s = -INFINITY; int e_l = 0;
      if (l32 < cs){
        float2 pk = pack[cb + l32];
        e_l = __float_as_int(pk.x);
        int vi = (int)pk.y;
        s = se2[e_l] + base + (float)(vi & 63) * wd + (float)(vi >> 6) * wg;
      }
      float m_c = s;
#pragma unroll
      for (int mm = 16; mm >= 1; mm >>= 1) m_c = fmaxf(m_c, __shfl_xor(m_c, mm, 32));
      float p = (l32 < cs) ? __expf(s - m_c) : 0.f;
      float l_c = p;
#pragma unroll
      for (int mm = 16; mm >= 1; mm >>= 1) l_c += __shfl_xor(l_c, mm, 32);
      float m_new = fmaxf(m_run, m_c);
      float f_old = __expf(m_run - m_new);
      float f_c = __expf(m_c - m_new);
#pragma unroll
      for (int r = 0; r < 4; r++){ a1[r] *= f_old; a2[r] *= f_old; }
      l_run = l_run * f_old + l_c * f_c;
      m_run = m_new;
      int jj = 0;
      for (; jj + 3 < cs; jj += 4){
        float w0 = __shfl(p, jj, 32) * f_c;
        float w1 = __shfl(p, jj + 1, 32) * f_c;
        float w2 = __shfl(p, jj + 2, 32) * f_c;
        float w3 = __shfl(p, jj + 3, 32) * f_c;
        int e0i = __shfl(e_l, jj, 32);
        int e1i = __shfl(e_l, jj + 1, 32);
        int e2i = __shfl(e_l, jj + 2, 32);
        int e3i = __shfl(e_l, jj + 3, 32);
        float4 q0 = ETq[(size_t)e0i * 32 + l32];
        float4 q1 = ETq[(size_t)e1i * 32 + l32];
        float4 q2 = ETq[(size_t)e2i * 32 + l32];
        float4 q3 = ETq[(size_t)e3i * 32 + l32];
        acc8(q0, w0, a1, a2);
        acc8(q1, w1, a1, a2);
        acc8(q2, w2, a1, a2);
        acc8(q3, w3, a1, a2);
      }
      for (; jj < cs; jj++){
        float w = __shfl(p, jj, 32) * f_c;
        int ei_ = __shfl(e_l, jj, 32);
        float4 q = ETq[(size_t)ei_ * 32 + l32];
        acc8(q, w, a1, a2);
      }
    }
  }
  float inv = l_run > 0.f ? 1.0f / l_run : 0.f;
  float dv = degV[n] * inv;
  float2 st;
  *(__half2*)&st.x = __floats2half2_rn(a2[0] * dv, a2[1] * dv);
  *(__half2*)&st.y = __floats2half2_rn(a2[2] * dv, a2[3] * dv);
  *(float2*)&Xv2h[(size_t)n * 64 + 2 * l32] = st;
  float2 h0 = __half22float2(*(const __half2*)&x0v2.x);
  float2 h1 = __half22float2(*(const __half2*)&x0v2.y);
  float2 xo;
  *(__half2*)&xo.x = __floats2half2_rn(0.45f * dv * (a1[0] + a2[0]) + 0.1f * h0.x,
                                       0.45f * dv * (a1[1] + a2[1]) + 0.1f * h0.y);
  *(__half2*)&xo.y = __floats2half2_rn(0.45f * dv * (a1[2] + a2[2]) + 0.1f * h1.x,
                                       0.45f * dv * (a1[3] + a2[3]) + 0.1f * h1.y);
  *(float2*)&xiH[(size_t)n * 64 + 2 * l32] = xo;
}

// pass3. ONE WAVE PER EDGE: 4x16-lane subgroups, 4 entries in flight.
__global__ __launch_bounds__(256) void k_agg3(const int* __restrict__ nodes, const int* __restrict__ eo,
    const float4* __restrict__ Xv2h4, const float* __restrict__ a_v2e, const float* __restrict__ esc,
    const float4* __restrict__ ETq, const float4* __restrict__ e0h4,
    int E, __half2* __restrict__ eiH){
  int lane = threadIdx.x & 63;
  int wave = threadIdx.x >> 6;
  int e = blockIdx.x * 4 + wave;
  if (e >= E) return;
  int b = eo[e], en = eo[e + 1];
  int l16 = lane & 15, q16 = lane >> 4;
  float a[8] = {0.f, 0.f, 0.f, 0.f, 0.f, 0.f, 0.f, 0.f};
  int k = b + q16;
  for (; k + 4 < en; k += 8){
    float w0 = a_v2e[k], w1 = a_v2e[k + 4];
    int n0 = nodes[k], n1 = nodes[k + 4];
    float4 v0 = Xv2h4[(size_t)n0 * 16 + l16];
    float4 v1 = Xv2h4[(size_t)n1 * 16 + l16];
    acc8h(v0, w0, a); acc8h(v1, w1, a);
  }
  for (; k < en; k += 4){
    float w = a_v2e[k];
    int n = nodes[k];
    float4 v = Xv2h4[(size_t)n * 16 + l16];
    acc8h(v, w, a);
  }
#pragma unroll
  for (int j = 0; j < 8; j++){
    a[j] += __shfl_xor(a[j], 16, 64);
    a[j] += __shfl_xor(a[j], 32, 64);
  }
  if (q16 == 0){
    float dE = esc[e];
    float4 q0 = ETq[(size_t)e * 32 + 2 * l16];
    float4 q1 = ETq[(size_t)e * 32 + 2 * l16 + 1];
    float2 x01 = __half22float2(*(const __half2*)&q0.x);
    float2 x23 = __half22float2(*(const __half2*)&q0.z);
    float2 x45 = __half22float2(*(const __half2*)&q1.x);
    float2 x67 = __half22float2(*(const __half2*)&q1.z);
    float4 ev = e0h4[(size_t)e * 16 + l16];
    float2 g0 = __half22float2(*(const __half2*)&ev.x);
    float2 g1 = __half22float2(*(const __half2*)&ev.y);
    float2 g2 = __half22float2(*(const __half2*)&ev.z);
    float2 g3 = __half22float2(*(const __half2*)&ev.w);
    float4 o;
    *(__half2*)&o.x = __floats2half2_rn(0.45f * (x01.x + a[0] * dE) + 0.1f * g0.x,
                                        0.45f * (x01.y + a[1] * dE) + 0.1f * g0.y);
    *(__half2*)&o.y = __floats2half2_rn(0.45f * (x23.x + a[2] * dE) + 0.1f * g1.x,
                                        0.45f * (x23.y + a[3] * dE) + 0.1f * g1.y);
    *(__half2*)&o.z = __floats2half2_rn(0.45f * (x45.x + a[4] * dE) + 0.1f * g2.x,
                                        0.45f * (x45.y + a[5] * dE) + 0.1f * g2.y);
    *(__half2*)&o.w = __floats2half2_rn(0.45f * (x67.x + a[6] * dE) + 0.1f * g3.x,
                                        0.45f * (x67.y + a[7] * dE) + 0.1f * g3.y);
    *(float4*)&eiH[(size_t)e * 64 + 4 * l16] = o;
  }
}

// GEMM body: 4 waves, 64 rows x 128 cols, K=128, fp16 A, residual folded into Wt.
// fp16 outputs staged through LDS for fully-coalesced 256B-row stores.
__device__ __forceinline__ void gemm_body(
    const _Float16* __restrict__ Ah, const _Float16* __restrict__ Wt,
    float* __restrict__ outf, _Float16* __restrict__ outh,
    const float* __restrict__ awA, const float* __restrict__ awB,
    float* __restrict__ sA, float* __restrict__ sB,
    int nrows, int do_relu, int blockRow0, _Float16 (*sh)[136]){
  int lane = threadIdx.x & 63, wave = threadIdx.x >> 6;
  int row0 = blockRow0 + wave * 16;
  int lm = lane & 15;
  int lk8 = (lane >> 4) * 8;
  int rbase = (lane >> 4) * 4;
  if (row0 < nrows){
    int arow = row0 + lm; if (arow >= nrows) arow = nrows - 1;
    f16x8 afrag[4];
#pragma unroll
    for (int ks = 0; ks < 4; ks++)
      afrag[ks] = *(const f16x8*)(Ah + (size_t)arow * 128 + ks * 32 + lk8);
    float da[4] = {0.f, 0.f, 0.f, 0.f}, db[4] = {0.f, 0.f, 0.f, 0.f};
    for (int t = 0; t < 8; t++){
      f32x4 acc = {0.f, 0.f, 0.f, 0.f};
#pragma unroll
      for (int ks = 0; ks < 4; ks++){
        f16x8 bf = *(const f16x8*)(Wt + (size_t)(t * 16 + lm) * 128 + ks * 32 + lk8);
        acc = __builtin_amdgcn_mfma_f32_16x16x32_f16(afrag[ks], bf, acc, 0, 0, 0);
      }
      int col = t * 16 + lm;
      float wa = 0.f, wb = 0.f;
      if (awA){ wa = awA[col]; wb = awB[col]; }
#pragma unroll
      for (int r = 0; r < 4; r++){
        int gr = row0 + rbase + r;
        float v = acc[r];
        if (do_relu) v = fmaxf(v, 0.f);
        if (outf && gr < nrows) outf[(size_t)gr * 128 + col] = v;
        if (outh) sh[wave * 16 + rbase + r][col] = (_Float16)v;
        if (gr < nrows){ da[r] += v * wa; db[r] += v * wb; }
      }
    }
    if (awA){
#pragma unroll
      for (int r = 0; r < 4; r++){
        float a = da[r], bb = db[r];
#pragma unroll
        for (int m = 8; m >= 1; m >>= 1){
          a += __shfl_xor(a, m, 64);
          bb += __shfl_xor(bb, m, 64);
        }
        int gr = row0 + rbase + r;
        if (lm == 0 && gr < nrows){ sA[gr] = a; sB[gr] = bb; }
      }
    }
  }
  if (outh){
    __syncthreads();
    for (int i = threadIdx.x; i < 64 * 16; i += 256){
      int rr = i >> 4, cc = (i & 15) * 8;
      int gr = blockRow0 + rr;
      if (gr < nrows)
        *(f16x8*)(outh + (size_t)gr * 128 + cc) = *(const f16x8*)&sh[rr][cc];
    }
  }
}

// merged x-GEMM + e-GEMM (block-range split); both emit linear fp16 (or f32 at i=3)
__global__ __launch_bounds__(256) void k_gemm2(
    const _Float16* __restrict__ Ax, const _Float16* __restrict__ Wx,
    const _Float16* __restrict__ Ae, const _Float16* __restrict__ Wte,
    float* __restrict__ outfx, _Float16* __restrict__ outhx,
    float* __restrict__ outfe, _Float16* __restrict__ outhe,
    const float* __restrict__ awAx, const float* __restrict__ awBx,
    float* __restrict__ sAx, float* __restrict__ sBx,
    const float* __restrict__ awAe, const float* __restrict__ awBe,
    float* __restrict__ sAe, float* __restrict__ sBe,
    int nrx, int nre, int nbx, int do_relu){
  __shared__ _Float16 sh[64][136];
  if ((int)blockIdx.x < nbx){
    gemm_body(Ax, Wx, outfx, outhx, awAx, awBx, sAx, sBx, nrx, do_relu,
              blockIdx.x * 64, sh);
  } else {
    gemm_body(Ae, Wte, outfe, outhe, awAe, awBe, sAe, sBe, nre, do_relu,
              (blockIdx.x - nbx) * 64, sh);
  }
}

// initial GEMM: A built from f32 x_in; out = relu(acc + bias); LDS-staged stores to
// xh AND x0h (both linear fp16); fused layer-0 x-scores.
__global__ __launch_bounds__(256) void k_gemm0(
    const float* __restrict__ Af, const _Float16* __restrict__ Wt,
    const float* __restrict__ bias,
    _Float16* __restrict__ outh, _Float16* __restrict__ outh2,
    const float* __restrict__ awA, const float* __restrict__ awB,
    float* __restrict__ sA, float* __restrict__ sB, int nrows){
  __shared__ _Float16 sh[64][136];
  int wave = threadIdx.x >> 6, lane = threadIdx.x & 63;
  int blockRow0 = blockIdx.x * 64;
  int row0 = blockRow0 + wave * 16;
  int lm = lane & 15;
  int lk8 = (lane >> 4) * 8;
  int rbase = (lane >> 4) * 4;
  if (row0 < nrows){
    int arow = row0 + lm; if (arow >= nrows) arow = nrows - 1;
    const float* ap = Af + (size_t)arow * 128;
    f16x8 afrag[4];
#pragma unroll
    for (int ks = 0; ks < 4; ks++){
      float4 v0 = *(const float4*)(ap + ks * 32 + lk8);
      float4 v1 = *(const float4*)(ap + ks * 32 + lk8 + 4);
      f16x8 a;
      a[0] = (_Float16)v0.x; a[1] = (_Float16)v0.y; a[2] = (_Float16)v0.z; a[3] = (_Float16)v0.w;
      a[4] = (_Float16)v1.x; a[5] = (_Float16)v1.y; a[6] = (_Float16)v1.z; a[7] = (_Float16)v1.w;
      afrag[ks] = a;
    }
    float da[4] = {0.f, 0.f, 0.f, 0.f}, db[4] = {0.f, 0.f, 0.f, 0.f};
    for (int t = 0; t < 8; t++){
      f32x4 acc = {0.f, 0.f, 0.f, 0.f};
#pragma unroll
      for (int ks = 0; ks < 4; ks++){
        f16x8 bf = *(const f16x8*)(Wt + (size_t)(t * 16 + lm) * 128 + ks * 32 + lk8);
        acc = __builtin_amdgcn_mfma_f32_16x16x32_f16(afrag[ks], bf, acc, 0, 0, 0);
      }
      int col = t * 16 + lm;
      float wa = awA[col], wb = awB[col];
      float bi = bias[col];
#pragma unroll
      for (int r = 0; r < 4; r++){
        int gr = row0 + rbase + r;
        float v = fmaxf(acc[r] + bi, 0.f);
        sh[wave * 16 + rbase + r][col] = (_Float16)v;
        if (gr < nrows){ da[r] += v * wa; db[r] += v * wb; }
      }
    }
#pragma unroll
    for (int r = 0; r < 4; r++){
      float a = da[r], bb = db[r];
#pragma unroll
      for (int m = 8; m >= 1; m >>= 1){
        a += __shfl_xor(a, m, 64);
        bb += __shfl_xor(bb, m, 64);
      }
      int gr = row0 + rbase + r;
      if (lm == 0 && gr < nrows){ sA[gr] = a; sB[gr] = bb; }
    }
  }
  __syncthreads();
  for (int i = threadIdx.x; i < 64 * 16; i += 256){
    int rr = i >> 4, cc = (i & 15) * 8;
    int gr = blockRow0 + rr;
    if (gr < nrows){
      f16x8 v = *(const f16x8*)&sh[rr][cc];
      *(f16x8*)(outh + (size_t)gr * 128 + cc) = v;
      *(f16x8*)(outh2 + (size_t)gr * 128 + cc) = v;
    }
  }
}

// ---- host ----------------------------------------------------------------

extern "C" void kernel_launch(void* const* d_in, const int* in_sizes, int n_in,
                              void* d_out, int out_size, void* d_ws, size_t ws_size,
                              hipStream_t stream) {
  const float* x_in     = (const float*)d_in[0];
  const float* e_in     = (const float*)d_in[1];
  const int*   hei      = (const int*)d_in[2];
  const float* dist_v2e = (const float*)d_in[3];
  const float* deg_v2e  = (const float*)d_in[4];
  const float* dist_e2v = (const float*)d_in[5];
  const float* deg_e2v  = (const float*)d_in[6];
  const float* W0       = (const float*)d_in[7];
  const float* b0       = (const float*)d_in[8];
  const float* Wn       = (const float*)d_in[9];
  const float* We       = (const float*)d_in[10];
  const float* attn_w   = (const float*)d_in[11];
  const float* attn_b   = (const float*)d_in[12];
  const float* wd_w     = (const float*)d_in[13];
  const float* wd_b     = (const float*)d_in[14];
  const float* wg_w     = (const float*)d_in[15];
  const float* wg_b     = (const float*)d_in[16];

  const int N   = in_sizes[0] / DD;
  const int E   = in_sizes[1] / DD;
  const int NNZ = in_sizes[2] / 2;
  const int* nodesArr = hei;
  const int* edgesArr = hei + NNZ;

  float* out_x = (float*)d_out;
  float* out_e = (float*)d_out + (size_t)N * DD;

  // aliases inside d_out (fully overwritten by final GEMMs):
  // x-region second half: xh (fp16). e-region: ET interleaved table (E x 512B).
  __half2* xh   = (__half2*)((char*)out_x + (size_t)N * DD * 2);
  _Float16* ETraw = (_Float16*)out_e;
  const float4* ETq = (const float4*)out_e;

  char* wsp = (char*)d_ws;
  auto alloc = [&](size_t bytes) -> void* {
    void* p = (void*)wsp;
    wsp += (bytes + 255) / 256 * 256;
    return p;
  };
  _Float16* x0h  = (_Float16*)alloc((size_t)N * DD * 2);  // x0 residual, fp16
  _Float16* Xv2h = (_Float16*)alloc((size_t)N * DD * 2);  // Xv2, fp16
  _Float16* xiH  = (_Float16*)alloc((size_t)N * DD * 2);  // xi, fp16
  _Float16* eiH  = (_Float16*)alloc((size_t)E * DD * 2);  // ei, fp16
  _Float16* e0h  = (_Float16*)alloc((size_t)E * DD * 2);  // e0 residual (= layer-0 ehL)
  _Float16* ehL  = (_Float16*)alloc((size_t)E * DD * 2);  // eh linear (layers 1..3)
  _Float16* Wt   = (_Float16*)alloc((size_t)9 * 16384 * 2);
  float* sx1   = (float*)alloc((size_t)N * 4);
  float* sx2   = (float*)alloc((size_t)N * 4);
  float* se1   = (float*)alloc((size_t)E * 4);
  float* se2   = (float*)alloc((size_t)E * 4);
  float* a_v2e = (float*)alloc((size_t)NNZ * 4);
  float* degV  = (float*)alloc((size_t)N * 4);
  float* degE  = (float*)alloc((size_t)E * 4);
  float* esc   = (float*)alloc((size_t)E * 4);
  float2* pack = (float2*)alloc((size_t)NNZ * 8);
  int* dV_i  = (int*)alloc((size_t)N * 4);
  int* no_   = (int*)alloc((size_t)(N + 1) * 4);
  int* nfill = (int*)alloc((size_t)N * 4);
  int* eo    = (int*)alloc((size_t)(E + 1) * 4);
  int* part  = (int*)alloc((size_t)SCAN_BLOCKS * 4);

  // ---- setup
  hipMemsetAsync(dV_i, 0, (size_t)N * 4, stream);
  k_edge_offsets<<<(E + 1 + 255) / 256, 256, 0, stream>>>(edgesArr, NNZ, E, eo);
  k_hist<<<(NNZ + 255) / 256, 256, 0, stream>>>(nodesArr, NNZ, dV_i);
  k_scan_partial<<<SCAN_BLOCKS, 256, 0, stream>>>(dV_i, N, part);
  k_scan_blocksums<<<1, SCAN_BLOCKS, 0, stream>>>(part);
  k_scan_apply<<<SCAN_BLOCKS, 256, 0, stream>>>(dV_i, N, NNZ, part, no_, nfill, degV);
  k_permpack<<<(NNZ + 255) / 256, 256, 0, stream>>>(nodesArr, edgesArr, dist_e2v, deg_e2v,
                                                    NNZ, nfill, pack);
  k_edge_deg<<<(E + 255) / 256, 256, 0, stream>>>(nodesArr, eo, E, dV_i, degE);
  k_wcast<<<(9 * 16384 + 255) / 256, 256, 0, stream>>>(W0, Wn, We, Wt);

  const float* aw1_0 = attn_w;          // aw[0,:d]
  const float* aw2_0 = attn_w + 128;    // aw[0,d:]

  // e0h (linear fp16 e_in) + layer-0 e-scores
  k_einit<<<(E + 3) / 4, 256, 0, stream>>>((const float2*)e_in, aw1_0, aw2_0,
                                            E, (__half2*)e0h, se1, se2);

  // x0 = relu(x_in @ W0 + b0): LDS-staged coalesced fp16 stores to xh, x0h; scores
  k_gemm0<<<(N + 63) / 64, 256, 0, stream>>>(x_in, Wt, b0,
      (_Float16*)xh, x0h, aw1_0, aw2_0, sx1, sx2, N);

  const int nbx = (N + 63) / 64, nbe = (E + 63) / 64;
  for (int i = 0; i < 4; i++){
    const float* aw1n = (i < 3) ? attn_w + (size_t)(i + 1) * 256        : nullptr;
    const float* aw2n = (i < 3) ? attn_w + (size_t)(i + 1) * 256 + 128  : nullptr;
    const _Float16* ehCur = (i == 0) ? e0h : ehL;

    // merged v2e softmax + pass1; writes FULL interleaved ET rows (Xe1 + eh)
    k_sma1<<<(E + 3) / 4, 256, 0, stream>>>(nodesArr, eo, sx1, se1,
        dist_v2e, deg_v2e, attn_b, wd_w, wd_b, wg_w, wg_b, i, degE,
        (const float4*)xh, ehCur, E, a_v2e, esc, ETraw);

    // e2v softmax + node aggregation (32-lane group per node, r7 variant)
    k_agg2f<<<(N + 7) / 8, 256, 0, stream>>>(pack, no_, se2, sx2,
        attn_b, wd_w, wd_b, wg_w, wg_b, i,
        ETq, degV, (const __half2*)x0h, N, (__half2*)Xv2h, (__half2*)xiH);

    // edge aggregation of Xv2 (wave per edge)
    k_agg3<<<(E + 3) / 4, 256, 0, stream>>>(nodesArr, eo, (const float4*)Xv2h,
        a_v2e, esc, ETq, (const float4*)e0h, E, (__half2*)eiH);

    // merged x+e GEMM (residual folded into Wt); linear fp16 outs (f32 at i=3)
    k_gemm2<<<nbx + nbe, 256, 0, stream>>>(
        xiH, Wt + (size_t)(1 + i) * 16384,
        eiH, Wt + (size_t)(5 + i) * 16384,
        (i == 3) ? out_x : nullptr, (i < 3) ? (_Float16*)xh : nullptr,
        (i == 3) ? out_e : nullptr, (i < 3) ? ehL : nullptr,
        aw1n, aw2n, sx1, sx2,
        aw2n, aw1n, se1, se2,
        N, E, nbx, i < 3 ? 1 : 0);
  }
}